// Round 3
// baseline (898.184 us; speedup 1.0000x reference)
//
#include <hip/hip_runtime.h>

#define BS   8
#define NCH  7
#define PX   409600      // 640*640
#define NBIN 65536
#define NCHK 256
#define WIN_LO 0x3000u   // LDS histogram window over top-16 bits: [0x3000, 0x4000)
#define WIN_SZ 4096
#define EPSF 1e-6f
#define NT   256
#define BPB  400         // blocks per batch: BPB*NT*4 == PX exactly

__device__ __forceinline__ float sigf(float x) {
    return 1.0f / (1.0f + __expf(-x));
}

__device__ __forceinline__ unsigned wred_u(unsigned v) {
    #pragma unroll
    for (int o = 32; o; o >>= 1) v += __shfl_down(v, o);
    return v;
}

__device__ __forceinline__ float wred_f(float v) {
    #pragma unroll
    for (int o = 32; o; o >>= 1) v += __shfl_down(v, o);
    return v;
}

// =====================================================================================
// two-level coalesced select: chunks[256] (chunk c = bins [c*256,(c+1)*256)), bins[65536]
// finds bin s.t. count(elements in bins >= bin) >= k, strictly < k above; rank in bin.
// Block-uniform call (all 256 threads).
// =====================================================================================
__device__ void select2(const unsigned* __restrict__ chunks,
                        const unsigned* __restrict__ bins,
                        unsigned k, unsigned* out_bin, unsigned* out_rank) {
    __shared__ unsigned cs[256];
    __shared__ unsigned sel_c, sel_r;
    int t = threadIdx.x;
    cs[t] = chunks[t];                 // coalesced
    __syncthreads();
    #pragma unroll
    for (int off = 1; off < 256; off <<= 1) {
        unsigned v = cs[t];
        unsigned a = (t + off < 256) ? cs[t + off] : 0u;
        __syncthreads();
        cs[t] = v + a;
        __syncthreads();
    }
    {
        unsigned sfx  = cs[t];
        unsigned sfx1 = (t < 255) ? cs[t + 1] : 0u;
        if (sfx >= k && sfx1 < k) { sel_c = (unsigned)t; sel_r = k - sfx1; }
    }
    __syncthreads();
    unsigned chunk = sel_c, krem = sel_r;
    cs[t] = bins[chunk * 256 + t];     // coalesced
    __syncthreads();
    #pragma unroll
    for (int off = 1; off < 256; off <<= 1) {
        unsigned v = cs[t];
        unsigned a = (t + off < 256) ? cs[t + off] : 0u;
        __syncthreads();
        cs[t] = v + a;
        __syncthreads();
    }
    {
        unsigned sfx  = cs[t];
        unsigned sfx1 = (t < 255) ? cs[t + 1] : 0u;
        if (sfx >= krem && sfx1 < krem) {
            *out_bin  = chunk * 256 + (unsigned)t;
            *out_rank = krem - sfx1;
        }
    }
    __syncthreads();
}

// =====================================================================================
// K1: single cold pass over ALL data + in-kernel threshold selection (last-block
// ticket, non-blocking — no cooperative launch, no grid.sync).
//   - packed-u16 LDS histogram window (8 KB -> LDS never caps occupancy)
//   - 18 L_s sums + 3 SPECULATIVE L_c sums under M=1 (valid whenever thr<=0,
//     which covers the inactive and bin-0-shortcut cases)
//   - last block per batch: select hi bin; bin0 -> thr=0; inactive -> thr=-1;
//     rare thr>0: solo exact refine + invalidate speculative sums (K2 recomputes)
// =====================================================================================
__global__ __launch_bounds__(256) void k_main(
        const float* __restrict__ preds, const int* __restrict__ labels,
        const int* __restrict__ mask,
        unsigned* __restrict__ hist1, unsigned* __restrict__ chunks1,
        unsigned* __restrict__ n_pos, unsigned* __restrict__ done1,
        float* __restrict__ thr, float* __restrict__ sums,
        unsigned* __restrict__ hist2, unsigned* __restrict__ chunks2) {
    const int tid = threadIdx.x;
    const int b   = blockIdx.y;
    const float* pr = preds + (size_t)b * NCH * PX;
    const int*   lb = labels + (size_t)b * NCH * PX;
    const int*   mk = mask + (size_t)b * PX;

    __shared__ unsigned lh32[WIN_SZ / 2];       // packed 2x u16 counts (max 1024/block)
    #pragma unroll
    for (int j = tid; j < WIN_SZ / 2; j += NT) lh32[j] = 0u;
    __syncthreads();

    const int g  = blockIdx.x * NT + tid;       // 0..102399, exact cover
    const int px = g * 4;

    // ---- all 15 dwordx4 loads issued straight-line ----
    float4 p6 = *(const float4*)(pr + 6 * PX + px);
    int4   m4 = *(const int4*)(mk + px);
    int4   l6 = *(const int4*)(lb + 6 * PX + px);
    float4 pc[6];
    int4   lc[6];
    #pragma unroll
    for (int c = 0; c < 6; c++) pc[c] = *(const float4*)(pr + c * PX + px);
    #pragma unroll
    for (int c = 0; c < 6; c++) lc[c] = *(const int4*)(lb + c * PX + px);

    float mm[4]  = {(float)m4.x, (float)m4.y, (float)m4.z, (float)m4.w};
    float p6a[4] = {p6.x, p6.y, p6.z, p6.w};
    float l6a[4] = {(float)l6.x, (float)l6.y, (float)l6.z, (float)l6.w};
    float pn[4], W[4];
    #pragma unroll
    for (int u = 0; u < 4; u++) {
        pn[u] = sigf(p6a[u]) * mm[u];
        W[u]  = (pn[u] >= 0.5f) ? 1.0f : 0.0f;
    }

    // ---- 18 L_s sums + 3 speculative (M=1) L_c sums: pure FMA chain, no branches ----
    float acc[21];
    #pragma unroll
    for (int j = 0; j < 21; j++) acc[j] = 0.f;
    #pragma unroll
    for (int c = 0; c < 6; c++) {
        float pcs[4] = {pc[c].x, pc[c].y, pc[c].z, pc[c].w};
        float lcs[4] = {(float)lc[c].x, (float)lc[c].y, (float)lc[c].z, (float)lc[c].w};
        #pragma unroll
        for (int u = 0; u < 4; u++) {
            float s = sigf(pcs[u]);
            float l = lcs[u];
            acc[c]      += s * l * W[u];   // sn[c]
            acc[6 + c]  += s * s * W[u];   // sp[c]
            acc[12 + c] += l * W[u];       // sl[c]
        }
    }
    #pragma unroll
    for (int u = 0; u < 4; u++) {
        float ln = l6a[u] * mm[u];
        acc[18] += pn[u] * ln;             // spec a0 (M=1)
        acc[19] += pn[u] * pn[u];          // spec a1
        acc[20] += ln;                     // spec a2
    }

    // ---- histogram / counts (branchy part last) ----
    unsigned pos_cnt = 0, zero_cnt = 0;
    #pragma unroll
    for (int u = 0; u < 4; u++) {
        if (W[u] != 0.0f) {
            pos_cnt++;
        } else {
            unsigned bits = __float_as_uint(pn[u]);
            if (bits == 0u) {
                zero_cnt++;
            } else {
                unsigned hb = bits >> 16;
                unsigned w  = hb - WIN_LO;
                if (w < WIN_SZ) {
                    atomicAdd(&lh32[w >> 1], 1u << ((w & 1) * 16));
                } else {   // rare fallback (pn < ~4.7e-10): keep global consistent
                    atomicAdd(&hist1[(size_t)b * NBIN + hb], 1u);
                    atomicAdd(&chunks1[b * NCHK + (hb >> 8)], 1u);
                }
            }
        }
    }
    __syncthreads();

    // flush LDS window histogram to global bins (coalesced)
    for (int j = tid; j < WIN_SZ; j += NT) {
        unsigned c = (lh32[j >> 1] >> ((j & 1) * 16)) & 0xFFFFu;
        if (c) atomicAdd(&hist1[(size_t)b * NBIN + WIN_LO + j], c);
    }
    // window chunk sums (chunks 48..63)
    __shared__ unsigned csum[256];
    {
        int chunk = tid >> 4, part = tid & 15;
        const unsigned* base = &lh32[(chunk * 256 + part * 16) >> 1];
        unsigned s = 0;
        #pragma unroll
        for (int w2 = 0; w2 < 8; w2++) { unsigned v = base[w2]; s += (v & 0xFFFFu) + (v >> 16); }
        csum[tid] = s;
    }
    __syncthreads();
    if (tid < 16) {
        unsigned s = 0;
        #pragma unroll
        for (int j = 0; j < 16; j++) s += csum[tid * 16 + j];
        if (s) atomicAdd(&chunks1[b * NCHK + 48 + tid], s);
    }

    // block-reduce pos/zero counts
    __shared__ unsigned ws2[2][4];
    unsigned pv = wred_u(pos_cnt), zv = wred_u(zero_cnt);
    int lane = tid & 63, wid = tid >> 6;
    if (lane == 0) { ws2[0][wid] = pv; ws2[1][wid] = zv; }
    __syncthreads();
    if (tid == 0) {
        unsigned pt = 0, zt = 0;
        #pragma unroll
        for (int w = 0; w < 4; w++) { pt += ws2[0][w]; zt += ws2[1][w]; }
        if (pt) atomicAdd(&n_pos[b], pt);
        if (zt) {
            atomicAdd(&hist1[(size_t)b * NBIN], zt);
            atomicAdd(&chunks1[b * NCHK], zt);
        }
    }

    // block-reduce the 21 sums: 18 L_s -> slots 3..20, 3 spec L_c -> slots 0..2
    __shared__ float red[4][21];
    #pragma unroll
    for (int j = 0; j < 21; j++) {
        float v = wred_f(acc[j]);
        if (lane == 0) red[wid][j] = v;
    }
    __syncthreads();
    if (tid < 21) {
        float tot = red[0][tid] + red[1][tid] + red[2][tid] + red[3][tid];
        int slot = (tid < 18) ? (3 + tid) : (tid - 18);
        atomicAdd(&sums[b * 21 + slot], tot);
    }

    // ---- last-block-per-batch: in-kernel selection (non-blocking ticket) ----
    __threadfence();
    __shared__ unsigned tick;
    if (tid == 0) tick = atomicAdd(&done1[b], 1u);
    __syncthreads();
    if (tick != (unsigned)(BPB - 1)) return;
    __threadfence();    // make all batch-b producers' writes visible

    unsigned np_ = n_pos[b];
    unsigned k = np_ * 3u;
    unsigned nneg = (unsigned)PX - np_;
    if (!(nneg > k && k > 0u)) {
        if (tid == 0) thr[b] = -1.0f;     // M = 1 everywhere: speculative sums valid
        return;
    }
    __shared__ unsigned rb, rr;
    select2(chunks1 + b * NCHK, hist1 + (size_t)b * NBIN, k, &rb, &rr);
    if (rb == 0u) {
        // bin 0: pn==0 pixels contribute 0 to every L_c sum under any M -> thr=0,
        // M = (pn>=0) == 1: speculative sums valid
        if (tid == 0) thr[b] = 0.0f;
        return;
    }

    // RARE path: exact low-16-bit refine by this block alone (not hit by bench data)
    unsigned hi = rb;
    unsigned* h2 = hist2 + (size_t)b * NBIN;
    unsigned* c2 = chunks2 + b * NCHK;
    for (int j = tid; j < NBIN; j += NT) h2[j] = 0u;
    for (int j = tid; j < NCHK; j += NT) c2[j] = 0u;
    __syncthreads();
    const float* pr6 = pr + (size_t)6 * PX;
    for (int gg = tid; gg < PX; gg += NT) {
        float pnx = sigf(pr6[gg]) * (float)mk[gg];
        if (pnx < 0.5f) {
            unsigned bits = __float_as_uint(pnx);
            if ((bits >> 16) == hi) {
                unsigned lo = bits & 0xFFFFu;
                atomicAdd(&h2[lo], 1u);
                atomicAdd(&c2[lo >> 8], 1u);
            }
        }
    }
    __syncthreads();
    __shared__ unsigned rb2, rr2;
    select2(c2, h2, rr, &rb2, &rr2);
    if (tid == 0) {
        thr[b] = __uint_as_float((hi << 16) | rb2);   // > 0 -> K2 recomputes L_c sums
        sums[b * 21 + 0] = 0.f;   // invalidate speculative sums
        sums[b * 21 + 1] = 0.f;
        sums[b * 21 + 2] = 0.f;
    }
}

// =====================================================================================
// K2: L_c sums ONLY when thr>0 (rare); global-last block emits the final losses.
// Common path per block: read thr, skip, ticket. ~free.
// =====================================================================================
__global__ __launch_bounds__(256) void k_lc(
        const float* __restrict__ preds, const int* __restrict__ labels,
        const int* __restrict__ mask, const float* __restrict__ thr,
        float* __restrict__ sums, unsigned* __restrict__ done2,
        float* __restrict__ out) {
    const int tid = threadIdx.x;
    const int b   = blockIdx.y;
    float thr_b = thr[b];

    if (thr_b > 0.0f) {          // rare: recompute the 3 thr-dependent sums
        const float* pr = preds + ((size_t)b * NCH + 6) * PX;
        const int*   lb = labels + ((size_t)b * NCH + 6) * PX;
        const int*   mk = mask + (size_t)b * PX;
        int g = blockIdx.x * NT + tid;
        int px = g * 4;
        float4 p6 = *(const float4*)(pr + px);
        int4   l4 = *(const int4*)(lb + px);
        int4   m4 = *(const int4*)(mk + px);
        float p6a[4] = {p6.x, p6.y, p6.z, p6.w};
        float la[4]  = {(float)l4.x, (float)l4.y, (float)l4.z, (float)l4.w};
        float mmx[4] = {(float)m4.x, (float)m4.y, (float)m4.z, (float)m4.w};
        float a0 = 0.f, a1 = 0.f, a2 = 0.f;
        #pragma unroll
        for (int u = 0; u < 4; u++) {
            float pnx = sigf(p6a[u]) * mmx[u];
            float Mi = (pnx >= thr_b) ? 1.0f : 0.0f;
            float ln = la[u] * mmx[u];
            a0 += pnx * ln * Mi;
            a1 += pnx * pnx * Mi;
            a2 += ln * Mi;
        }
        __shared__ float red[4][3];
        int lane = tid & 63, wid = tid >> 6;
        float v0 = wred_f(a0), v1 = wred_f(a1), v2 = wred_f(a2);
        if (lane == 0) { red[wid][0] = v0; red[wid][1] = v1; red[wid][2] = v2; }
        __syncthreads();
        if (tid < 3) {
            float tot = red[0][tid] + red[1][tid] + red[2][tid] + red[3][tid];
            atomicAdd(&sums[b * 21 + tid], tot);
        }
    }

    // ---- grid-last block computes the final losses ----
    __threadfence();
    __shared__ unsigned tick;
    if (tid == 0) tick = atomicAdd(done2, 1u);
    __syncthreads();
    if (tick != (unsigned)(BPB * BS) - 1u) return;
    __threadfence();

    float Lc = 0.f, Ls = 0.f;
    if (tid < BS) {
        const float* s = sums + tid * 21;
        Lc = 1.0f - (2.0f * s[0]) / (s[1] + s[2] + EPSF);
        float a = 0.f;
        #pragma unroll
        for (int c = 0; c < 6; c++)
            a += (2.0f * s[3 + c]) / (s[9 + c] + s[15 + c] + EPSF);
        Ls = 1.0f - a * (1.0f / 6.0f);
    }
    #pragma unroll
    for (int o = 4; o; o >>= 1) { Lc += __shfl_down(Lc, o); Ls += __shfl_down(Ls, o); }
    if (tid == 0) {
        float lc_m = Lc * (1.0f / (float)BS);
        float ls_m = Ls * (1.0f / (float)BS);
        out[0] = lc_m;
        out[1] = ls_m;
        out[2] = 0.7f * lc_m + 0.3f * ls_m;
    }
}

extern "C" void kernel_launch(void* const* d_in, const int* in_sizes, int n_in,
                              void* d_out, int out_size, void* d_ws, size_t ws_size,
                              hipStream_t stream) {
    const float* preds = (const float*)d_in[0];
    const int* labels  = (const int*)d_in[1];
    const int* mask    = (const int*)d_in[2];
    float* out = (float*)d_out;

    // workspace layout (u32/f32 words); [hist1 .. sums] is the contiguous zero region
    unsigned* hist1   = (unsigned*)d_ws;              // BS * NBIN
    unsigned* chunks1 = hist1 + (size_t)BS * NBIN;    // BS * NCHK
    unsigned* n_pos   = chunks1 + (size_t)BS * NCHK;  // BS
    unsigned* done1   = n_pos + BS;                   // BS
    unsigned* done2   = done1 + BS;                   // 8 (only [0] used)
    float*    thr     = (float*)(done2 + 8);          // BS
    float*    sums    = thr + BS;                     // BS * 21
    unsigned* hist2   = (unsigned*)(sums + BS * 21);  // BS * NBIN  (zeroed on demand)
    unsigned* chunks2 = hist2 + (size_t)BS * NBIN;    // BS * NCHK  (zeroed on demand)

    size_t zero_words = (size_t)BS * NBIN + (size_t)BS * NCHK + BS + BS + 8 + BS
                      + (size_t)BS * 21;
    hipMemsetAsync(d_ws, 0, zero_words * sizeof(unsigned), stream);

    hipLaunchKernelGGL(k_main, dim3(BPB, BS), dim3(NT), 0, stream,
                       preds, labels, mask, hist1, chunks1, n_pos, done1,
                       thr, sums, hist2, chunks2);

    hipLaunchKernelGGL(k_lc, dim3(BPB, BS), dim3(NT), 0, stream,
                       preds, labels, mask, thr, sums, done2, out);
}

// Round 4
// 220.983 us; speedup vs baseline: 4.0645x; 4.0645x over previous
//
#include <hip/hip_runtime.h>

#define BS   8
#define NCH  7
#define PX   409600      // 640*640
#define NBIN 65536
#define NCHK 256
#define EPSF 1e-6f
#define NT   256
#define BPB  200         // blocks per batch: BPB*NT*2groups*4px == PX exactly

__device__ __forceinline__ float sigf(float x) {
    return 1.0f / (1.0f + __expf(-x));
}

__device__ __forceinline__ unsigned wred_u(unsigned v) {
    #pragma unroll
    for (int o = 32; o; o >>= 1) v += __shfl_down(v, o);
    return v;
}

__device__ __forceinline__ float wred_f(float v) {
    #pragma unroll
    for (int o = 32; o; o >>= 1) v += __shfl_down(v, o);
    return v;
}

// =====================================================================================
// two-level coalesced select over chunks[256] / bins[65536]: finds bin s.t. suffix
// count >= k, strictly < k above; rank within bin. Block-uniform call, 256 threads.
// =====================================================================================
__device__ void select2(const unsigned* __restrict__ chunks,
                        const unsigned* __restrict__ bins,
                        unsigned k, unsigned* out_bin, unsigned* out_rank) {
    __shared__ unsigned cs[256];
    int t = threadIdx.x;
    cs[t] = chunks[t];
    __syncthreads();
    #pragma unroll
    for (int off = 1; off < 256; off <<= 1) {
        unsigned v = cs[t];
        unsigned a = (t + off < 256) ? cs[t + off] : 0u;
        __syncthreads();
        cs[t] = v + a;
        __syncthreads();
    }
    {
        unsigned sfx  = cs[t];
        unsigned sfx1 = (t < 255) ? cs[t + 1] : 0u;
        if (sfx >= k && sfx1 < k) { *out_bin = (unsigned)t; *out_rank = k - sfx1; }
    }
    __syncthreads();
    unsigned chunk = *out_bin, krem = *out_rank;
    cs[t] = bins[chunk * 256 + t];
    __syncthreads();
    #pragma unroll
    for (int off = 1; off < 256; off <<= 1) {
        unsigned v = cs[t];
        unsigned a = (t + off < 256) ? cs[t + off] : 0u;
        __syncthreads();
        cs[t] = v + a;
        __syncthreads();
    }
    {
        unsigned sfx  = cs[t];
        unsigned sfx1 = (t < 255) ? cs[t + 1] : 0u;
        if (sfx >= krem && sfx1 < krem) {
            *out_bin  = chunk * 256 + (unsigned)t;
            *out_rank = krem - sfx1;
        }
    }
    __syncthreads();
}

// =====================================================================================
// K1: pure load+FMA cold pass. NO histogram, NO global atomics, NO memset dependency.
//   - per thread: 2 groups x 4 px; 15 dwordx4 loads per group
//   - outputs per block (plain stores): 21 partial sums (18 L_s + 3 speculative M=1
//     L_c) and packed pos/zero counts. Selection needs only these counts unless the
//     rare exact-threshold path fires (decided in k_sel).
// =====================================================================================
__global__ __launch_bounds__(256) void k_main(
        const float* __restrict__ preds, const int* __restrict__ labels,
        const int* __restrict__ mask,
        float* __restrict__ psum,        // [BS][21][BPB]
        unsigned* __restrict__ ppos,     // [BS][BPB]
        unsigned* __restrict__ pzero,    // [BS][BPB]
        unsigned* __restrict__ done) {
    const int tid = threadIdx.x;
    const int b = blockIdx.y, cb = blockIdx.x;
    if (b == 0 && cb == 0 && tid == 0) *done = 0u;   // re-arm k_sel's ticket

    const float* pr = preds + (size_t)b * NCH * PX;
    const int*   lb = labels + (size_t)b * NCH * PX;
    const int*   mk = mask + (size_t)b * PX;

    float acc[21];
    #pragma unroll
    for (int j = 0; j < 21; j++) acc[j] = 0.f;
    unsigned cnt = 0;                     // pos | (zero<<16), max 8 each

    #pragma unroll
    for (int it = 0; it < 2; ++it) {
        const int g  = cb * NT + tid + it * (BPB * NT);
        const int px = g * 4;
        // ---- all 15 dwordx4 loads, straight-line, no intervening atomics/branches ----
        float4 p6 = *(const float4*)(pr + 6 * PX + px);
        int4   m4 = *(const int4*)(mk + px);
        int4   l6 = *(const int4*)(lb + 6 * PX + px);
        float4 pc[6];
        int4   lc[6];
        #pragma unroll
        for (int c = 0; c < 6; c++) pc[c] = *(const float4*)(pr + c * PX + px);
        #pragma unroll
        for (int c = 0; c < 6; c++) lc[c] = *(const int4*)(lb + c * PX + px);

        float mm[4]  = {(float)m4.x, (float)m4.y, (float)m4.z, (float)m4.w};
        float p6a[4] = {p6.x, p6.y, p6.z, p6.w};
        float l6a[4] = {(float)l6.x, (float)l6.y, (float)l6.z, (float)l6.w};
        float pn[4], W[4];
        #pragma unroll
        for (int u = 0; u < 4; u++) {
            pn[u] = sigf(p6a[u]) * mm[u];
            bool pos = (pn[u] >= 0.5f);
            W[u] = pos ? 1.0f : 0.0f;
            // zero ⟺ bits==0 (sigmoid>0 always, so pn==0 ⟺ mask==0)
            cnt += pos ? 1u : (__float_as_uint(pn[u]) == 0u ? 0x10000u : 0u);
        }
        #pragma unroll
        for (int c = 0; c < 6; c++) {
            float pcs[4] = {pc[c].x, pc[c].y, pc[c].z, pc[c].w};
            float lcs[4] = {(float)lc[c].x, (float)lc[c].y,
                            (float)lc[c].z, (float)lc[c].w};
            #pragma unroll
            for (int u = 0; u < 4; u++) {
                float s = sigf(pcs[u]);
                float l = lcs[u];
                acc[c]      += s * l * W[u];   // sn[c]
                acc[6 + c]  += s * s * W[u];   // sp[c]
                acc[12 + c] += l * W[u];       // sl[c]
            }
        }
        #pragma unroll
        for (int u = 0; u < 4; u++) {
            float ln = l6a[u] * mm[u];
            acc[18] += pn[u] * ln;             // spec a0 (M=1)
            acc[19] += pn[u] * pn[u];          // spec a1
            acc[20] += ln;                     // spec a2 (ln in {0,1} so ln^2==ln)
        }
    }

    // ---- block reduce -> plain stores (no atomics, no init required) ----
    __shared__ float    red[4][21];
    __shared__ unsigned cred[4];
    int lane = tid & 63, wid = tid >> 6;
    #pragma unroll
    for (int j = 0; j < 21; j++) {
        float v = wred_f(acc[j]);
        if (lane == 0) red[wid][j] = v;
    }
    unsigned cv = wred_u(cnt);
    if (lane == 0) cred[wid] = cv;
    __syncthreads();
    if (tid < 21) {
        float tot = red[0][tid] + red[1][tid] + red[2][tid] + red[3][tid];
        psum[((size_t)b * 21 + tid) * BPB + cb] = tot;   // [b][s][cb]: coalesced read later
    }
    if (tid == 21) {
        unsigned ct = cred[0] + cred[1] + cred[2] + cred[3];
        ppos[b * BPB + cb]  = ct & 0xFFFFu;
        pzero[b * BPB + cb] = ct >> 16;
    }
}

// =====================================================================================
// K2 (k_sel): 8 blocks, one per batch. Reduce partials; decide path:
//   !active or k >= nzneg  -> speculative sums exact (thr<=0 or excludes only
//                             zero-contribution pixels)  [always hit on bench data]
//   else (rare)            -> solo exact two-level selection + L_c rescan
// Then an 8-block ticket (16 fences total — cheap) emits the final losses.
// =====================================================================================
__global__ __launch_bounds__(256) void k_sel(
        const float* __restrict__ preds, const int* __restrict__ labels,
        const int* __restrict__ mask,
        const float* __restrict__ psum, const unsigned* __restrict__ ppos,
        const unsigned* __restrict__ pzero,
        unsigned* __restrict__ histws, unsigned* __restrict__ chunkws,
        float* __restrict__ lcls,        // [BS][2]
        unsigned* __restrict__ done, float* __restrict__ out) {
    const int tid = threadIdx.x;
    const int b = blockIdx.x;
    int lane = tid & 63, wid = tid >> 6;

    // ---- reduce counts ----
    __shared__ unsigned uR[4][2];
    unsigned npv = (tid < BPB) ? ppos[b * BPB + tid] : 0u;
    unsigned zcv = (tid < BPB) ? pzero[b * BPB + tid] : 0u;
    unsigned r0 = wred_u(npv), r1 = wred_u(zcv);
    if (lane == 0) { uR[wid][0] = r0; uR[wid][1] = r1; }
    __syncthreads();
    const unsigned np = uR[0][0] + uR[1][0] + uR[2][0] + uR[3][0];
    const unsigned zc = uR[0][1] + uR[1][1] + uR[2][1] + uR[3][1];

    // ---- reduce the 21 sums into LDS ----
    __shared__ float S[21];
    if (tid < 21) S[tid] = 0.f;
    __syncthreads();
    for (int i = tid; i < 21 * BPB; i += NT) {
        atomicAdd(&S[i / BPB], psum[(size_t)b * 21 * BPB + i]);   // coalesced reads
    }
    __syncthreads();

    const unsigned k = np * 3u;
    const bool active = ((unsigned)PX - np > k) && (k > 0u);
    const unsigned nzneg = (unsigned)PX - np - zc;   // negatives with pn > 0

    float Lc_b;
    if (!active || k >= nzneg) {
        // thr <= 0, or thr == smallest nonzero negative: either way the excluded
        // pixels have pn==0 => mask==0 => zero contribution. Spec sums exact.
        Lc_b = 1.0f - 2.0f * S[18] / (S[19] + S[20] + EPSF);
    } else {
        // -------- RARE exact path (not hit by bench data; correctness only) --------
        unsigned* h1 = histws + (size_t)b * NBIN;
        unsigned* c1 = chunkws + (size_t)b * NCHK;
        const float* pr6 = preds + ((size_t)b * NCH + 6) * PX;
        const int*   lb6 = labels + ((size_t)b * NCH + 6) * PX;
        const int*   mk  = mask + (size_t)b * PX;

        for (int j = tid; j < NBIN; j += NT) h1[j] = 0u;
        for (int j = tid; j < NCHK; j += NT) c1[j] = 0u;
        __syncthreads();
        for (int gg = tid; gg < PX; gg += NT) {
            float pnx = sigf(pr6[gg]) * (float)mk[gg];
            if (pnx < 0.5f) {
                unsigned bits = __float_as_uint(pnx);
                if (bits) {
                    atomicAdd(&h1[bits >> 16], 1u);
                    atomicAdd(&c1[bits >> 24], 1u);
                }
            }
        }
        __syncthreads();
        if (tid == 0) { atomicAdd(&h1[0], zc); atomicAdd(&c1[0], zc); }  // zeros are negatives
        __syncthreads();

        __shared__ unsigned rb, rr, rb2, rr2;
        select2(c1, h1, k, &rb, &rr);
        float thrv;
        if (rb == 0u) {
            thrv = 0.0f;
        } else {
            unsigned hi = rb;
            for (int j = tid; j < NBIN; j += NT) h1[j] = 0u;
            for (int j = tid; j < NCHK; j += NT) c1[j] = 0u;
            __syncthreads();
            for (int gg = tid; gg < PX; gg += NT) {
                float pnx = sigf(pr6[gg]) * (float)mk[gg];
                if (pnx < 0.5f) {
                    unsigned bits = __float_as_uint(pnx);
                    if (bits && (bits >> 16) == hi) {
                        unsigned lo = bits & 0xFFFFu;
                        atomicAdd(&h1[lo], 1u);
                        atomicAdd(&c1[lo >> 8], 1u);
                    }
                }
            }
            __syncthreads();
            select2(c1, h1, rr, &rb2, &rr2);
            thrv = __uint_as_float((hi << 16) | rb2);
        }
        // exact L_c sums with M = (pn >= thrv)
        float a0 = 0.f, a1 = 0.f, a2 = 0.f;
        for (int gg = tid; gg < PX; gg += NT) {
            float m   = (float)mk[gg];
            float pnx = sigf(pr6[gg]) * m;
            if (pnx >= thrv) {
                float ln = (float)lb6[gg] * m;
                a0 += pnx * ln;
                a1 += pnx * pnx;
                a2 += ln;
            }
        }
        __shared__ float aR[4][3];
        float v0 = wred_f(a0), v1 = wred_f(a1), v2 = wred_f(a2);
        if (lane == 0) { aR[wid][0] = v0; aR[wid][1] = v1; aR[wid][2] = v2; }
        __syncthreads();
        float A0 = aR[0][0] + aR[1][0] + aR[2][0] + aR[3][0];
        float A1 = aR[0][1] + aR[1][1] + aR[2][1] + aR[3][1];
        float A2 = aR[0][2] + aR[1][2] + aR[2][2] + aR[3][2];
        Lc_b = 1.0f - 2.0f * A0 / (A1 + A2 + EPSF);
    }

    // L_s from the 18 reduced sums
    float ls_acc = 0.f;
    #pragma unroll
    for (int c = 0; c < 6; c++)
        ls_acc += (2.0f * S[c]) / (S[6 + c] + S[12 + c] + EPSF);
    float Ls_b = 1.0f - ls_acc * (1.0f / 6.0f);

    if (tid == 0) {
        lcls[b * 2]     = Lc_b;
        lcls[b * 2 + 1] = Ls_b;
    }

    // ---- 8-block ticket -> last block emits final losses ----
    __shared__ unsigned tick;
    if (tid == 0) {
        __threadfence();
        tick = atomicAdd(done, 1u);
    }
    __syncthreads();
    if (tick != (unsigned)(BS - 1)) return;
    __threadfence();

    float Lc = 0.f, Ls = 0.f;
    if (tid < BS) { Lc = lcls[tid * 2]; Ls = lcls[tid * 2 + 1]; }
    #pragma unroll
    for (int o = 4; o; o >>= 1) { Lc += __shfl_down(Lc, o); Ls += __shfl_down(Ls, o); }
    if (tid == 0) {
        float lc_m = Lc * (1.0f / (float)BS);
        float ls_m = Ls * (1.0f / (float)BS);
        out[0] = lc_m;
        out[1] = ls_m;
        out[2] = 0.7f * lc_m + 0.3f * ls_m;
    }
}

extern "C" void kernel_launch(void* const* d_in, const int* in_sizes, int n_in,
                              void* d_out, int out_size, void* d_ws, size_t ws_size,
                              hipStream_t stream) {
    const float* preds = (const float*)d_in[0];
    const int* labels  = (const int*)d_in[1];
    const int* mask    = (const int*)d_in[2];
    float* out = (float*)d_out;

    // workspace (u32/f32 words) — nothing needs pre-zeroing
    float*    psum    = (float*)d_ws;                        // BS*21*BPB
    unsigned* ppos    = (unsigned*)(psum + BS * 21 * BPB);   // BS*BPB
    unsigned* pzero   = ppos + BS * BPB;                     // BS*BPB
    unsigned* done    = pzero + BS * BPB;                    // 1
    float*    lcls    = (float*)(done + 8);                  // BS*2 (pad to 8)
    unsigned* histws  = (unsigned*)(lcls + BS * 2);          // BS*NBIN (rare path only)
    unsigned* chunkws = histws + (size_t)BS * NBIN;          // BS*NCHK (rare path only)
    (void)chunkws;

    hipLaunchKernelGGL(k_main, dim3(BPB, BS), dim3(NT), 0, stream,
                       preds, labels, mask, psum, ppos, pzero, done);

    hipLaunchKernelGGL(k_sel, dim3(BS), dim3(NT), 0, stream,
                       preds, labels, mask, psum, ppos, pzero,
                       histws, chunkws, lcls, done, out);
}